// Round 1
// baseline (5543.158 us; speedup 1.0000x reference)
//
#include <hip/hip_runtime.h>

#define F 128
#define ROWS_PER_BLOCK 80

// ---------------------------------------------------------------------------
// wx = X @ W.T + b   (X: [n,128] f32, W: [128,128] f32 row-major, b: [128])
// W staged transposed in LDS: Wt[k][j] = W[j][k] so lane-consecutive j reads
// are bank-conflict-free. Each thread computes 4 rows x 1 feature.
// ---------------------------------------------------------------------------
__global__ __launch_bounds__(256) void gemm_wx_kernel(
    const float* __restrict__ X, const float* __restrict__ W,
    const float* __restrict__ bias, float* __restrict__ out, int nrows)
{
    __shared__ float Wt[F][F];   // 64 KiB
    __shared__ float xs[8][F];   //  4 KiB

    int t = threadIdx.x;
    for (int idx = t; idx < F * F; idx += 256) {
        int j = idx >> 7, k = idx & (F - 1);
        Wt[k][j] = W[idx];
    }
    __syncthreads();

    int j  = t & (F - 1);
    int rg = t >> 7;                       // 0 or 1 -> rows rg*4 .. rg*4+3
    float bj = bias[j];
    long base = (long)blockIdx.x * ROWS_PER_BLOCK;

    for (int r0 = 0; r0 < ROWS_PER_BLOCK; r0 += 8) {
        long row0 = base + r0;
        __syncthreads();
        for (int idx = t; idx < 8 * F; idx += 256) {
            int rr = idx >> 7, kk = idx & (F - 1);
            long rowi = row0 + rr;
            xs[rr][kk] = (rowi < nrows) ? X[rowi * F + kk] : 0.0f;
        }
        __syncthreads();

        float acc0 = 0.f, acc1 = 0.f, acc2 = 0.f, acc3 = 0.f;
#pragma unroll 4
        for (int k = 0; k < F; ++k) {
            float w = Wt[k][j];            // conflict-free (lane-consecutive j)
            acc0 += xs[rg * 4 + 0][k] * w; // xs reads: same addr across lanes
            acc1 += xs[rg * 4 + 1][k] * w; //           -> LDS broadcast
            acc2 += xs[rg * 4 + 2][k] * w;
            acc3 += xs[rg * 4 + 3][k] * w;
        }

        float acc[4] = {acc0, acc1, acc2, acc3};
#pragma unroll
        for (int r = 0; r < 4; ++r) {
            long rowi = row0 + rg * 4 + r;
            if (rowi < nrows) out[rowi * F + j] = acc[r] + bj;
        }
    }
}

// ---------------------------------------------------------------------------
// For each edge e: temp[row[e]] += (row!=col) * ev[e]^2 * wx[col[e]]
// 32 lanes per edge, float4 per lane (128 features). Gather is a coalesced
// 512B segment; scatter is 4 scalar f32 atomics per lane (410M total).
// ---------------------------------------------------------------------------
__global__ __launch_bounds__(256) void edge_scatter_kernel(
    const int* __restrict__ rowi, const int* __restrict__ coli,
    const float* __restrict__ ev, const float* __restrict__ wx,
    float* __restrict__ temp, int E)
{
    int tid = blockIdx.x * 256 + threadIdx.x;
    int e   = tid >> 5;
    if (e >= E) return;
    int lane = tid & 31;

    int r = rowi[e];
    int c = coli[e];
    if (r == c) return;
    float v = ev[e];
    v = v * v;

    const float4 wv = *reinterpret_cast<const float4*>(wx + (size_t)c * F + lane * 4);
    float* tp = temp + (size_t)r * F + lane * 4;
    atomicAdd(tp + 0, v * wv.x);
    atomicAdd(tp + 1, v * wv.y);
    atomicAdd(tp + 2, v * wv.z);
    atomicAdd(tp + 3, v * wv.w);
}

// ---------------------------------------------------------------------------
// out = wx * temp (in place on d_out, float4)
// ---------------------------------------------------------------------------
__global__ __launch_bounds__(256) void finalize_kernel(
    float* __restrict__ out, const float* __restrict__ temp, int n4)
{
    int i = blockIdx.x * 256 + threadIdx.x;
    if (i >= n4) return;
    float4 o  = reinterpret_cast<float4*>(out)[i];
    float4 tv = reinterpret_cast<const float4*>(temp)[i];
    o.x *= tv.x; o.y *= tv.y; o.z *= tv.z; o.w *= tv.w;
    reinterpret_cast<float4*>(out)[i] = o;
}

extern "C" void kernel_launch(void* const* d_in, const int* in_sizes, int n_in,
                              void* d_out, int out_size, void* d_ws, size_t ws_size,
                              hipStream_t stream)
{
    const float* X  = (const float*)d_in[0];
    const int*   ei = (const int*)d_in[1];   // [2, E] int32 (JAX x64 disabled)
    const float* ev = (const float*)d_in[2];
    const float* W  = (const float*)d_in[3];
    const float* b  = (const float*)d_in[4];
    float* out = (float*)d_out;

    int nrows = in_sizes[0] / F;
    int E     = in_sizes[2];
    float* temp = (float*)d_ws;              // [nrows, 128] f32 = 51.2 MB

    // temp must be zero every call (harness poisons ws once, never restores)
    hipMemsetAsync(d_ws, 0, (size_t)nrows * F * sizeof(float), stream);

    int gblocks = (nrows + ROWS_PER_BLOCK - 1) / ROWS_PER_BLOCK;
    gemm_wx_kernel<<<gblocks, 256, 0, stream>>>(X, W, b, out, nrows);

    long ethreads = (long)E * 32;
    int  eblocks  = (int)((ethreads + 255) / 256);
    edge_scatter_kernel<<<eblocks, 256, 0, stream>>>(ei, ei + E, ev, out, temp, E);

    int n4 = nrows * F / 4;
    finalize_kernel<<<(n4 + 255) / 256, 256, 0, stream>>>(out, temp, n4);
}

// Round 2
// 1006.608 us; speedup vs baseline: 5.5068x; 5.5068x over previous
//
#include <hip/hip_runtime.h>

#define F 128
#define ROWS_PER_BLOCK 80

// ---------------------------------------------------------------------------
// wx = X @ W.T + b
// ---------------------------------------------------------------------------
__global__ __launch_bounds__(256) void gemm_wx_kernel(
    const float* __restrict__ X, const float* __restrict__ W,
    const float* __restrict__ bias, float* __restrict__ out, int nrows)
{
    __shared__ float Wt[F][F];   // 64 KiB
    __shared__ float xs[8][F];   //  4 KiB

    int t = threadIdx.x;
    for (int idx = t; idx < F * F; idx += 256) {
        int j = idx >> 7, k = idx & (F - 1);
        Wt[k][j] = W[idx];
    }
    __syncthreads();

    int j  = t & (F - 1);
    int rg = t >> 7;
    float bj = bias[j];
    long base = (long)blockIdx.x * ROWS_PER_BLOCK;

    for (int r0 = 0; r0 < ROWS_PER_BLOCK; r0 += 8) {
        long row0 = base + r0;
        __syncthreads();
        for (int idx = t; idx < 8 * F; idx += 256) {
            int rr = idx >> 7, kk = idx & (F - 1);
            long rowi = row0 + rr;
            xs[rr][kk] = (rowi < nrows) ? X[rowi * F + kk] : 0.0f;
        }
        __syncthreads();

        float acc0 = 0.f, acc1 = 0.f, acc2 = 0.f, acc3 = 0.f;
#pragma unroll 4
        for (int k = 0; k < F; ++k) {
            float w = Wt[k][j];
            acc0 += xs[rg * 4 + 0][k] * w;
            acc1 += xs[rg * 4 + 1][k] * w;
            acc2 += xs[rg * 4 + 2][k] * w;
            acc3 += xs[rg * 4 + 3][k] * w;
        }

        float acc[4] = {acc0, acc1, acc2, acc3};
#pragma unroll
        for (int r = 0; r < 4; ++r) {
            long rowi = row0 + rg * 4 + r;
            if (rowi < nrows) out[rowi * F + j] = acc[r] + bj;
        }
    }
}

// ---------------------------------------------------------------------------
// CSR build: histogram of row indices (int atomics on 400KB, L2-friendly)
// ---------------------------------------------------------------------------
__global__ __launch_bounds__(256) void count_rows_kernel(
    const int* __restrict__ rowi, int* __restrict__ counts, int E)
{
    int i = blockIdx.x * 256 + threadIdx.x;
    if (i < E) atomicAdd(&counts[rowi[i]], 1);
}

// ---------------------------------------------------------------------------
// Single-block exclusive scan of counts[n] -> off[n+1], cursor[n]
// ---------------------------------------------------------------------------
__global__ __launch_bounds__(1024) void scan_kernel(
    const int* __restrict__ counts, int* __restrict__ off,
    int* __restrict__ cursor, int n)
{
    __shared__ int partial[1024];
    int t = threadIdx.x;
    int chunk = (n + 1023) / 1024;
    int lo = t * chunk;
    int hi = min(lo + chunk, n);

    int s = 0;
    for (int i = lo; i < hi; ++i) s += counts[i];
    partial[t] = s;
    __syncthreads();

    for (int d = 1; d < 1024; d <<= 1) {
        int v = (t >= d) ? partial[t - d] : 0;
        __syncthreads();
        partial[t] += v;
        __syncthreads();
    }

    int running = (t == 0) ? 0 : partial[t - 1];
    for (int i = lo; i < hi; ++i) {
        off[i] = running;
        cursor[i] = running;
        running += counts[i];
    }
    if (t == 1023) off[n] = partial[1023];
}

// ---------------------------------------------------------------------------
// Bucket fill: recs[pos] = (col, val^2); diagonal edges stored with val^2 = 0
// ---------------------------------------------------------------------------
__global__ __launch_bounds__(256) void fill_buckets_kernel(
    const int* __restrict__ rowi, const int* __restrict__ coli,
    const float* __restrict__ ev, int* __restrict__ cursor,
    int2* __restrict__ recs, int E)
{
    int i = blockIdx.x * 256 + threadIdx.x;
    if (i >= E) return;
    int r = rowi[i];
    int c = coli[i];
    float v = ev[i];
    float v2 = (r != c) ? v * v : 0.0f;
    int pos = atomicAdd(&cursor[r], 1);
    recs[pos] = make_int2(c, __float_as_int(v2));
}

// ---------------------------------------------------------------------------
// One wave per row: acc = sum_e val2[e] * wx[col[e]]; out[row] = wx[row]*acc
// Records read through scalar path (uniform address), wx gathered as
// coalesced 512B float2 segments (LLC-resident).
// ---------------------------------------------------------------------------
__global__ __launch_bounds__(256) void aggregate_kernel(
    const int* __restrict__ off, const int2* __restrict__ recs,
    const float* __restrict__ wx, float* __restrict__ out, int n)
{
    int wid  = (blockIdx.x * 256 + threadIdx.x) >> 6;  // one wave per row
    int lane = threadIdx.x & 63;
    if (wid >= n) return;

    int start = __builtin_amdgcn_readfirstlane(off[wid]);
    int end   = __builtin_amdgcn_readfirstlane(off[wid + 1]);

    const float* wxl = wx + (size_t)lane * 2;
    float accx = 0.f, accy = 0.f;

#pragma unroll 2
    for (int e = start; e < end; ++e) {
        int2 rec = recs[e];                       // uniform addr -> s_load
        float v  = __int_as_float(rec.y);
        const float2 wv = *reinterpret_cast<const float2*>(wxl + (size_t)rec.x * F);
        accx = fmaf(v, wv.x, accx);
        accy = fmaf(v, wv.y, accy);
    }

    const float2 wr = *reinterpret_cast<const float2*>(wxl + (size_t)wid * F);
    float2 o;
    o.x = wr.x * accx;
    o.y = wr.y * accy;
    *reinterpret_cast<float2*>(out + (size_t)wid * F + lane * 2) = o;
}

// ---------------------------------------------------------------------------
// Fallback path (round-1, proven): atomic scatter + finalize
// ---------------------------------------------------------------------------
__global__ __launch_bounds__(256) void edge_scatter_kernel(
    const int* __restrict__ rowi, const int* __restrict__ coli,
    const float* __restrict__ ev, const float* __restrict__ wx,
    float* __restrict__ temp, int E)
{
    int tid = blockIdx.x * 256 + threadIdx.x;
    int e   = tid >> 5;
    if (e >= E) return;
    int lane = tid & 31;

    int r = rowi[e];
    int c = coli[e];
    if (r == c) return;
    float v = ev[e];
    v = v * v;

    const float4 wv = *reinterpret_cast<const float4*>(wx + (size_t)c * F + lane * 4);
    float* tp = temp + (size_t)r * F + lane * 4;
    atomicAdd(tp + 0, v * wv.x);
    atomicAdd(tp + 1, v * wv.y);
    atomicAdd(tp + 2, v * wv.z);
    atomicAdd(tp + 3, v * wv.w);
}

__global__ __launch_bounds__(256) void finalize_kernel(
    float* __restrict__ out, const float* __restrict__ temp, int n4)
{
    int i = blockIdx.x * 256 + threadIdx.x;
    if (i >= n4) return;
    float4 o  = reinterpret_cast<float4*>(out)[i];
    float4 tv = reinterpret_cast<const float4*>(temp)[i];
    o.x *= tv.x; o.y *= tv.y; o.z *= tv.z; o.w *= tv.w;
    reinterpret_cast<float4*>(out)[i] = o;
}

extern "C" void kernel_launch(void* const* d_in, const int* in_sizes, int n_in,
                              void* d_out, int out_size, void* d_ws, size_t ws_size,
                              hipStream_t stream)
{
    const float* X  = (const float*)d_in[0];
    const int*   ei = (const int*)d_in[1];   // [2, E] int32
    const float* ev = (const float*)d_in[2];
    const float* W  = (const float*)d_in[3];
    const float* b  = (const float*)d_in[4];
    float* out = (float*)d_out;

    int nrows = in_sizes[0] / F;
    int E     = in_sizes[2];
    const int* rowi = ei;
    const int* coli = ei + E;

    // --- CSR-path workspace layout ---
    char* p = (char*)d_ws;
    float* wx = (float*)p;            p += (size_t)nrows * F * sizeof(float);
    int* counts = (int*)p;            p += (size_t)nrows * sizeof(int);
    int* off    = (int*)p;            p += (size_t)(nrows + 1) * sizeof(int);
    int* cursor = (int*)p;            p += (size_t)nrows * sizeof(int);
    p = (char*)(((uintptr_t)p + 15) & ~(uintptr_t)15);
    int2* recs  = (int2*)p;           p += (size_t)E * sizeof(int2);
    size_t need = (size_t)(p - (char*)d_ws);

    int gblocks = (nrows + ROWS_PER_BLOCK - 1) / ROWS_PER_BLOCK;
    int eblocks = (E + 255) / 256;

    if (ws_size >= need) {
        // ---------- CSR path ----------
        hipMemsetAsync(counts, 0, (size_t)nrows * sizeof(int), stream);
        gemm_wx_kernel<<<gblocks, 256, 0, stream>>>(X, W, b, wx, nrows);
        count_rows_kernel<<<eblocks, 256, 0, stream>>>(rowi, counts, E);
        scan_kernel<<<1, 1024, 0, stream>>>(counts, off, cursor, nrows);
        fill_buckets_kernel<<<eblocks, 256, 0, stream>>>(rowi, coli, ev, cursor, recs, E);
        int ablocks = (nrows * 4 + 255) / 256 + ((nrows * 4) % 256 ? 0 : 0);
        ablocks = ((long)nrows * 64 + 255) / 256;   // one wave (64 lanes) per row
        aggregate_kernel<<<ablocks, 256, 0, stream>>>(off, recs, wx, out, nrows);
    } else {
        // ---------- fallback: atomic scatter (round-1) ----------
        float* temp = (float*)d_ws;   // [nrows, 128]
        hipMemsetAsync(temp, 0, (size_t)nrows * F * sizeof(float), stream);
        gemm_wx_kernel<<<gblocks, 256, 0, stream>>>(X, W, b, out, nrows);
        long ethreads = (long)E * 32;
        int  eblocks32 = (int)((ethreads + 255) / 256);
        edge_scatter_kernel<<<eblocks32, 256, 0, stream>>>(rowi, coli, ev, out, temp, E);
        int n4 = nrows * F / 4;
        finalize_kernel<<<(n4 + 255) / 256, 256, 0, stream>>>(out, temp, n4);
    }
}

// Round 3
// 706.307 us; speedup vs baseline: 7.8481x; 1.4252x over previous
//
#include <hip/hip_runtime.h>
#include <hip/hip_bf16.h>

#define F 128
#define ROWS_PER_BLOCK 80

// ---------------------------------------------------------------------------
// wx = X @ W.T + b  -> f32 (wxf) and optional bf16 copy (wxh) for gathers
// ---------------------------------------------------------------------------
__global__ __launch_bounds__(256) void gemm_wx_kernel(
    const float* __restrict__ X, const float* __restrict__ W,
    const float* __restrict__ bias, float* __restrict__ wxf,
    __hip_bfloat16* __restrict__ wxh, int nrows, int writeH)
{
    __shared__ float Wt[F][F];   // 64 KiB
    __shared__ float xs[8][F];   //  4 KiB

    int t = threadIdx.x;
    for (int idx = t; idx < F * F; idx += 256) {
        int j = idx >> 7, k = idx & (F - 1);
        Wt[k][j] = W[idx];
    }
    __syncthreads();

    int j  = t & (F - 1);
    int rg = t >> 7;
    float bj = bias[j];
    long base = (long)blockIdx.x * ROWS_PER_BLOCK;

    for (int r0 = 0; r0 < ROWS_PER_BLOCK; r0 += 8) {
        long row0 = base + r0;
        __syncthreads();
        for (int idx = t; idx < 8 * F; idx += 256) {
            int rr = idx >> 7, kk = idx & (F - 1);
            long rowi = row0 + rr;
            xs[rr][kk] = (rowi < nrows) ? X[rowi * F + kk] : 0.0f;
        }
        __syncthreads();

        float acc0 = 0.f, acc1 = 0.f, acc2 = 0.f, acc3 = 0.f;
#pragma unroll 4
        for (int k = 0; k < F; ++k) {
            float w = Wt[k][j];
            acc0 += xs[rg * 4 + 0][k] * w;
            acc1 += xs[rg * 4 + 1][k] * w;
            acc2 += xs[rg * 4 + 2][k] * w;
            acc3 += xs[rg * 4 + 3][k] * w;
        }

        float acc[4] = {acc0, acc1, acc2, acc3};
#pragma unroll
        for (int r = 0; r < 4; ++r) {
            long rowi = row0 + rg * 4 + r;
            if (rowi < nrows) {
                float v = acc[r] + bj;
                wxf[rowi * F + j] = v;
                if (writeH) wxh[rowi * F + j] = __float2bfloat16(v);
            }
        }
    }
}

// ---------------------------------------------------------------------------
// Histogram of (row, virtual-xcd) where vxcd = blockIdx & vmask. Count and
// fill use the SAME grid + edge->thread mapping, so counts match fills
// regardless of actual block->XCD assignment (locality is best-effort).
// ---------------------------------------------------------------------------
__global__ __launch_bounds__(256) void count_rows_kernel(
    const int* __restrict__ rowi, int* __restrict__ counts, int E, int vmask)
{
    int i = blockIdx.x * 256 + threadIdx.x;
    if (i < E) {
        int nw = vmask + 1;
        atomicAdd(&counts[rowi[i] * nw + (blockIdx.x & vmask)], 1);
    }
}

// ---------------------------------------------------------------------------
// Multi-block exclusive scan over n8 counts (n8 % 4 == 0).
// scan1: per-block (1024 elems) local scan -> off, block total -> btot
// scan2: single block scans btot -> bbase, writes off[n8] = grand total
// scan3: off[i] += bbase[block]; cursor[i] = off[i]
// ---------------------------------------------------------------------------
__global__ __launch_bounds__(256) void scan1_kernel(
    const int* __restrict__ counts, int* __restrict__ off,
    int* __restrict__ btot, int n8)
{
    __shared__ int sdata[256];
    int t = threadIdx.x;
    int gi = blockIdx.x * 256 + t;          // int4 index
    bool ok = (gi * 4 < n8);
    int4 c = ok ? reinterpret_cast<const int4*>(counts)[gi] : make_int4(0,0,0,0);
    int s = c.x + c.y + c.z + c.w;
    sdata[t] = s;
    __syncthreads();
#pragma unroll
    for (int d = 1; d < 256; d <<= 1) {
        int v = (t >= d) ? sdata[t - d] : 0;
        __syncthreads();
        sdata[t] += v;
        __syncthreads();
    }
    int incl = sdata[t];
    int excl = incl - s;
    if (ok) {
        int4 o;
        o.x = excl; o.y = o.x + c.x; o.z = o.y + c.y; o.w = o.z + c.z;
        reinterpret_cast<int4*>(off)[gi] = o;
    }
    if (t == 255) btot[blockIdx.x] = incl;
}

__global__ __launch_bounds__(1024) void scan2_kernel(
    const int* __restrict__ btot, int* __restrict__ bbase,
    int* __restrict__ off, int nb, int n8)
{
    __shared__ int sdata[1024];
    int t = threadIdx.x;
    int v = (t < nb) ? btot[t] : 0;
    sdata[t] = v;
    __syncthreads();
#pragma unroll
    for (int d = 1; d < 1024; d <<= 1) {
        int u = (t >= d) ? sdata[t - d] : 0;
        __syncthreads();
        sdata[t] += u;
        __syncthreads();
    }
    if (t < nb) bbase[t] = sdata[t] - v;
    if (t == 1023) off[n8] = sdata[1023];
}

__global__ __launch_bounds__(256) void scan3_kernel(
    int* __restrict__ off, int* __restrict__ cursor,
    const int* __restrict__ bbase, int n8)
{
    int t = threadIdx.x;
    int gi = blockIdx.x * 256 + t;
    if (gi * 4 >= n8) return;
    int base = bbase[blockIdx.x];
    int4 o = reinterpret_cast<int4*>(off)[gi];
    o.x += base; o.y += base; o.z += base; o.w += base;
    reinterpret_cast<int4*>(off)[gi] = o;
    reinterpret_cast<int4*>(cursor)[gi] = o;
}

// ---------------------------------------------------------------------------
// Bucket fill: recs[pos] = (col, val^2); diagonal stored with val^2 = 0.
// Sub-segment chosen by blockIdx & vmask (same mapping as count).
// ---------------------------------------------------------------------------
__global__ __launch_bounds__(256) void fill_buckets_kernel(
    const int* __restrict__ rowi, const int* __restrict__ coli,
    const float* __restrict__ ev, int* __restrict__ cursor,
    int2* __restrict__ recs, int E, int vmask)
{
    int i = blockIdx.x * 256 + threadIdx.x;
    if (i >= E) return;
    int r = rowi[i];
    int c = coli[i];
    float v = ev[i];
    float v2 = (r != c) ? v * v : 0.0f;
    int nw = vmask + 1;
    int pos = atomicAdd(&cursor[r * nw + (blockIdx.x & vmask)], 1);
    recs[pos] = make_int2(c, __float_as_int(v2));
}

// ---------------------------------------------------------------------------
// One wave per row: acc = sum_e v2[e] * wx[col[e]]; out[row] = wxf[row]*acc.
// Row's records = union of its nw adjacent sub-segments: [off[r*nw], off[r*nw+nw])
// ---------------------------------------------------------------------------
template <int BF16>
__global__ __launch_bounds__(256) void aggregate_kernel(
    const int* __restrict__ off, const int2* __restrict__ recs,
    const float* __restrict__ wxf, const __hip_bfloat16* __restrict__ wxh,
    float* __restrict__ out, int n, int nw)
{
    int wid  = (blockIdx.x * 256 + threadIdx.x) >> 6;
    int lane = threadIdx.x & 63;
    if (wid >= n) return;

    int start = __builtin_amdgcn_readfirstlane(off[wid * nw]);
    int end   = __builtin_amdgcn_readfirstlane(off[wid * nw + nw]);

    float accx = 0.f, accy = 0.f;
    int e = start;
    for (; e + 1 < end; e += 2) {
        int2 r0 = recs[e];
        int2 r1 = recs[e + 1];
        float v0 = __int_as_float(r0.y);
        float v1 = __int_as_float(r1.y);
        if (BF16) {
            __hip_bfloat162 h0 = *reinterpret_cast<const __hip_bfloat162*>(
                wxh + (size_t)r0.x * F + lane * 2);
            __hip_bfloat162 h1 = *reinterpret_cast<const __hip_bfloat162*>(
                wxh + (size_t)r1.x * F + lane * 2);
            accx = fmaf(v0, __low2float(h0), accx);
            accy = fmaf(v0, __high2float(h0), accy);
            accx = fmaf(v1, __low2float(h1), accx);
            accy = fmaf(v1, __high2float(h1), accy);
        } else {
            float2 g0 = *reinterpret_cast<const float2*>(wxf + (size_t)r0.x * F + lane * 2);
            float2 g1 = *reinterpret_cast<const float2*>(wxf + (size_t)r1.x * F + lane * 2);
            accx = fmaf(v0, g0.x, accx);
            accy = fmaf(v0, g0.y, accy);
            accx = fmaf(v1, g1.x, accx);
            accy = fmaf(v1, g1.y, accy);
        }
    }
    if (e < end) {
        int2 r0 = recs[e];
        float v0 = __int_as_float(r0.y);
        if (BF16) {
            __hip_bfloat162 h0 = *reinterpret_cast<const __hip_bfloat162*>(
                wxh + (size_t)r0.x * F + lane * 2);
            accx = fmaf(v0, __low2float(h0), accx);
            accy = fmaf(v0, __high2float(h0), accy);
        } else {
            float2 g0 = *reinterpret_cast<const float2*>(wxf + (size_t)r0.x * F + lane * 2);
            accx = fmaf(v0, g0.x, accx);
            accy = fmaf(v0, g0.y, accy);
        }
    }

    float2 wr = *reinterpret_cast<const float2*>(wxf + (size_t)wid * F + lane * 2);
    float2 o;
    o.x = wr.x * accx;
    o.y = wr.y * accy;
    *reinterpret_cast<float2*>(out + (size_t)wid * F + lane * 2) = o;
}

// ---------------------------------------------------------------------------
// Last-resort fallback (round-1): atomic scatter + finalize
// ---------------------------------------------------------------------------
__global__ __launch_bounds__(256) void edge_scatter_kernel(
    const int* __restrict__ rowi, const int* __restrict__ coli,
    const float* __restrict__ ev, const float* __restrict__ wx,
    float* __restrict__ temp, int E)
{
    int tid = blockIdx.x * 256 + threadIdx.x;
    int e   = tid >> 5;
    if (e >= E) return;
    int lane = tid & 31;
    int r = rowi[e];
    int c = coli[e];
    if (r == c) return;
    float v = ev[e];
    v = v * v;
    const float4 wv = *reinterpret_cast<const float4*>(wx + (size_t)c * F + lane * 4);
    float* tp = temp + (size_t)r * F + lane * 4;
    atomicAdd(tp + 0, v * wv.x);
    atomicAdd(tp + 1, v * wv.y);
    atomicAdd(tp + 2, v * wv.z);
    atomicAdd(tp + 3, v * wv.w);
}

__global__ __launch_bounds__(256) void finalize_kernel(
    float* __restrict__ out, const float* __restrict__ temp, int n4)
{
    int i = blockIdx.x * 256 + threadIdx.x;
    if (i >= n4) return;
    float4 o  = reinterpret_cast<float4*>(out)[i];
    float4 tv = reinterpret_cast<const float4*>(temp)[i];
    o.x *= tv.x; o.y *= tv.y; o.z *= tv.z; o.w *= tv.w;
    reinterpret_cast<float4*>(out)[i] = o;
}

extern "C" void kernel_launch(void* const* d_in, const int* in_sizes, int n_in,
                              void* d_out, int out_size, void* d_ws, size_t ws_size,
                              hipStream_t stream)
{
    const float* X  = (const float*)d_in[0];
    const int*   ei = (const int*)d_in[1];   // [2, E] int32
    const float* ev = (const float*)d_in[2];
    const float* W  = (const float*)d_in[3];
    const float* b  = (const float*)d_in[4];
    float* out = (float*)d_out;

    int nrows = in_sizes[0] / F;
    int E     = in_sizes[2];
    const int* rowi = ei;
    const int* coli = ei + E;

    int gblocks = (nrows + ROWS_PER_BLOCK - 1) / ROWS_PER_BLOCK;
    int eblocks = (E + 255) / 256;

    // Try NW=8 (XCD-privatized) with bf16 gather; degrade gracefully.
    for (int attempt = 0; attempt < 2; ++attempt) {
        int nw      = attempt == 0 ? 8 : 1;
        int useBF16 = attempt == 0 ? 1 : 0;
        int n8 = nrows * nw;
        int nb = (n8 + 1023) / 1024;
        if (nb > 1024) continue;

        char* p = (char*)d_ws;
        float* wxf = (float*)p;          p += (size_t)nrows * F * sizeof(float);
        __hip_bfloat16* wxh = (__hip_bfloat16*)p;
        if (useBF16)                     p += (size_t)nrows * F * sizeof(__hip_bfloat16);
        int* counts = (int*)p;           p += (size_t)n8 * sizeof(int);   // reused as cursor
        int* off    = (int*)p;           p += (size_t)(n8 + 1) * sizeof(int);
        int* btot   = (int*)p;           p += (size_t)nb * sizeof(int);
        int* bbase  = (int*)p;           p += (size_t)nb * sizeof(int);
        p = (char*)(((uintptr_t)p + 15) & ~(uintptr_t)15);
        int2* recs  = (int2*)p;          p += (size_t)E * sizeof(int2);
        size_t need = (size_t)(p - (char*)d_ws);
        if (ws_size < need) continue;

        hipMemsetAsync(counts, 0, (size_t)n8 * sizeof(int), stream);
        gemm_wx_kernel<<<gblocks, 256, 0, stream>>>(X, W, b, wxf, wxh, nrows, useBF16);
        count_rows_kernel<<<eblocks, 256, 0, stream>>>(rowi, counts, E, nw - 1);
        scan1_kernel<<<nb, 256, 0, stream>>>(counts, off, btot, n8);
        scan2_kernel<<<1, 1024, 0, stream>>>(btot, bbase, off, nb, n8);
        scan3_kernel<<<nb, 256, 0, stream>>>(off, counts /*cursor*/, bbase, n8);
        fill_buckets_kernel<<<eblocks, 256, 0, stream>>>(rowi, coli, ev,
                                                         counts /*cursor*/, recs, E, nw - 1);
        int ablocks = (int)(((long)nrows * 64 + 255) / 256);
        if (useBF16)
            aggregate_kernel<1><<<ablocks, 256, 0, stream>>>(off, recs, wxf, wxh, out, nrows, nw);
        else
            aggregate_kernel<0><<<ablocks, 256, 0, stream>>>(off, recs, wxf, wxh, out, nrows, nw);
        return;
    }

    // ---------- last resort: atomic scatter ----------
    float* temp = (float*)d_ws;   // [nrows, 128]
    hipMemsetAsync(temp, 0, (size_t)nrows * F * sizeof(float), stream);
    gemm_wx_kernel<<<gblocks, 256, 0, stream>>>(X, W, b, out, (__hip_bfloat16*)0, nrows, 0);
    long ethreads = (long)E * 32;
    int  eblocks32 = (int)((ethreads + 255) / 256);
    edge_scatter_kernel<<<eblocks32, 256, 0, stream>>>(rowi, coli, ev, out, temp, E);
    int n4 = nrows * F / 4;
    finalize_kernel<<<(n4 + 255) / 256, 256, 0, stream>>>(out, temp, n4);
}